// Round 1
// baseline (262.863 us; speedup 1.0000x reference)
//
#include <hip/hip_runtime.h>
#include <hip/hip_bf16.h>

#define HH 96
#define WW 96
#define HWs 9216
#define NB 2
#define BN_EPS 1e-5f

// ---- workspace layout (float offsets) ----
#define OFF_WCAT1 0                       // 256x256
#define OFF_WCAT2 65536                   // 128x64
#define OFF_S1    73728                   // 256
#define OFF_T1    73984                   // 256
#define OFF_S2    74240                   // 128
#define OFF_T2    74368                   // 128
#define OFF_S3    74496                   // 256
#define OFF_T3    74752                   // 256
#define OFF_ST1   75008                   // [b][256][HW]: rows 0-127 = value, 128-191 = k1, 192-255 = q1
#define OFF_ST2   (OFF_ST1 + NB*256*HWs)  // [b][128][HW]: rows 0-63 = key, 64-127 = query
// context aliases st1 rows 128..255 (k1/q1 dead after stage2)

// ---------------- prep: fold BN into (s,t) epilogues, concat weights ----------------
__global__ __launch_bounds__(256) void prep_kernel(
    const float* __restrict__ fk_w1, const float* __restrict__ fk_b1, const float* __restrict__ fk_bn1,
    const float* __restrict__ fk_w2, const float* __restrict__ fk_b2, const float* __restrict__ fk_bn2,
    const float* __restrict__ fq_w1, const float* __restrict__ fq_b1, const float* __restrict__ fq_bn1,
    const float* __restrict__ fq_w2, const float* __restrict__ fq_b2, const float* __restrict__ fq_bn2,
    const float* __restrict__ fv_w,  const float* __restrict__ fv_b,
    const float* __restrict__ W_b,   float* __restrict__ ws)
{
  int i = blockIdx.x * 256 + threadIdx.x;
  if (i < 65536) {
    int o = i >> 8, c = i & 255;
    float v;
    if (o < 128)      v = fv_w[o * 256 + c];
    else if (o < 192) v = fk_w1[(o - 128) * 256 + c];
    else              v = fq_w1[(o - 192) * 256 + c];
    ws[OFF_WCAT1 + i] = v;
  } else if (i < 73728) {
    int j = i - 65536; int o = j >> 6, c = j & 63;
    ws[OFF_WCAT2 + j] = (o < 64) ? fk_w2[o * 64 + c] : fq_w2[(o - 64) * 64 + c];
  } else if (i < 73984) {
    int o = i - 73728;
    float s, t;
    if (o < 128) { s = 1.0f; t = fv_b[o]; }
    else if (o < 192) {
      int j = o - 128;
      float g = fk_bn1[j], be = fk_bn1[64 + j], m = fk_bn1[128 + j], v = fk_bn1[192 + j];
      s = g * rsqrtf(v + BN_EPS); t = (fk_b1[j] - m) * s + be;
    } else {
      int j = o - 192;
      float g = fq_bn1[j], be = fq_bn1[64 + j], m = fq_bn1[128 + j], v = fq_bn1[192 + j];
      s = g * rsqrtf(v + BN_EPS); t = (fq_b1[j] - m) * s + be;
    }
    ws[OFF_S1 + o] = s; ws[OFF_T1 + o] = t;
  } else if (i < 74112) {
    int o = i - 73984;
    float s, t;
    if (o < 64) {
      float g = fk_bn2[o], be = fk_bn2[64 + o], m = fk_bn2[128 + o], v = fk_bn2[192 + o];
      s = g * rsqrtf(v + BN_EPS); t = (fk_b2[o] - m) * s + be;
    } else {
      int j = o - 64;
      float g = fq_bn2[j], be = fq_bn2[64 + j], m = fq_bn2[128 + j], v = fq_bn2[192 + j];
      s = g * rsqrtf(v + BN_EPS); t = (fq_b2[j] - m) * s + be;
    }
    ws[OFF_S2 + o] = s; ws[OFF_T2 + o] = t;
  } else if (i < 74368) {
    int o = i - 74112;
    ws[OFF_S3 + o] = 1.0f; ws[OFF_T3 + o] = W_b[o];
  }
}

// ---------------- generic f32 GEMM: C[o][n] = sum_k A[o][k]*B[k][n], epilogue y=acc*s+t (+relu) ----------------
// A: MxK row-major. B rows stride HWs. C rows stride HWs. batch via blockIdx.z.
__global__ __launch_bounds__(256) void gemm_f32(
    const float* __restrict__ A, const float* __restrict__ B0, const float* __restrict__ B1,
    float* __restrict__ C, const float* __restrict__ S, const float* __restrict__ T,
    int M, int K, int m_split, int relu_start, long bStrideB, long bStrideC)
{
  __shared__ float As[16][68];
  __shared__ float Bs[16][68];
  const int tid = threadIdx.x;
  const int nb = blockIdx.x, mb = blockIdx.y, bb = blockIdx.z;
  const int m0 = mb * 64, n0 = nb * 64;
  const float* B = ((m0 >= m_split) ? B1 : B0) + (size_t)bb * bStrideB;
  float* Cb = C + (size_t)bb * bStrideC;

  float acc[4][4] = {{0.f}};
  const int la_m = tid >> 2, la_k = (tid & 3) * 4;
  const int lb_k = tid >> 4, lb_n = (tid & 15) * 4;
  const int tm = (tid >> 4) * 4, tn = (tid & 15) * 4;

  for (int k0 = 0; k0 < K; k0 += 16) {
    float4 a4 = *reinterpret_cast<const float4*>(A + (size_t)(m0 + la_m) * K + k0 + la_k);
    float4 b4 = *reinterpret_cast<const float4*>(B + (size_t)(k0 + lb_k) * HWs + n0 + lb_n);
    As[la_k + 0][la_m] = a4.x; As[la_k + 1][la_m] = a4.y;
    As[la_k + 2][la_m] = a4.z; As[la_k + 3][la_m] = a4.w;
    *reinterpret_cast<float4*>(&Bs[lb_k][lb_n]) = b4;
    __syncthreads();
#pragma unroll
    for (int k = 0; k < 16; k++) {
      float4 av = *reinterpret_cast<const float4*>(&As[k][tm]);
      float4 bv = *reinterpret_cast<const float4*>(&Bs[k][tn]);
      float a_[4] = {av.x, av.y, av.z, av.w};
      float b_[4] = {bv.x, bv.y, bv.z, bv.w};
#pragma unroll
      for (int i = 0; i < 4; i++)
#pragma unroll
        for (int j = 0; j < 4; j++) acc[i][j] += a_[i] * b_[j];
    }
    __syncthreads();
  }
#pragma unroll
  for (int i = 0; i < 4; i++) {
    int o = m0 + tm + i;
    float s = S[o], t = T[o];
    bool relu = (o >= relu_start);
    float4 r;
    r.x = acc[i][0] * s + t; r.y = acc[i][1] * s + t;
    r.z = acc[i][2] * s + t; r.w = acc[i][3] * s + t;
    if (relu) {
      r.x = fmaxf(r.x, 0.f); r.y = fmaxf(r.y, 0.f);
      r.z = fmaxf(r.z, 0.f); r.w = fmaxf(r.w, 0.f);
    }
    *reinterpret_cast<float4*>(Cb + (size_t)o * HWs + n0 + tn) = r;
  }
}

// ---------------- attention: 8x8 pixel tile, 64 threads, halo-staged LDS ----------------
__global__ __launch_bounds__(64) void attn_kernel(const float* __restrict__ st1,
                                                  const float* __restrict__ st2)
{
  __shared__ float4 tile4[4][14][17];   // [c4][y][x], x-stride 17 float4s to spread banks
  const int tid = threadIdx.x;
  const int tx = tid & 7, ty = tid >> 3;
  const int bb = blockIdx.z;
  const int x0 = blockIdx.x * 8, y0 = blockIdx.y * 8;
  const float* key   = st2 + (size_t)bb * 128 * HWs;
  const float* query = key + (size_t)64 * HWs;
  const float* value = st1 + (size_t)bb * 256 * HWs;        // rows 0..127
  float* ctxb = const_cast<float*>(st1) + (size_t)bb * 256 * HWs + (size_t)128 * HWs; // alias rows 128..255
  const int px = x0 + tx, py = y0 + ty;
  const int n = py * WW + px;

  auto stage = [&](const float* __restrict__ src, int cbase) {
#pragma unroll
    for (int it = 0; it < 13; ++it) {
      int idx = it * 64 + tid;
      if (idx < 784) {
        int xx = idx % 14; int rest = idx / 14;
        int yy = rest % 14; int c4 = rest / 14;
        int gy = y0 - 3 + yy, gx = x0 - 3 + xx;
        float4 v = {0.f, 0.f, 0.f, 0.f};
        if (gy >= 0 && gy < HH && gx >= 0 && gx < WW) {
          const float* p = src + (size_t)(cbase + c4 * 4) * HWs + gy * WW + gx;
          v.x = p[0]; v.y = p[HWs]; v.z = p[2 * HWs]; v.w = p[3 * HWs];
        }
        tile4[c4][yy][xx] = v;
      }
    }
  };

  float sim[49];
#pragma unroll
  for (int p = 0; p < 49; p++) sim[p] = 0.f;

#pragma unroll 1
  for (int ch = 0; ch < 64; ch += 16) {
    __syncthreads();
    stage(key, ch);
    __syncthreads();
    float4 q[4];
#pragma unroll
    for (int c4 = 0; c4 < 4; c4++) {
      const float* qp = query + (size_t)(ch + c4 * 4) * HWs + n;
      q[c4].x = qp[0]; q[c4].y = qp[HWs]; q[c4].z = qp[2 * HWs]; q[c4].w = qp[3 * HWs];
    }
#pragma unroll
    for (int dy = 0; dy < 7; dy++)
#pragma unroll
      for (int dx = 0; dx < 7; dx++) {
        float acc = 0.f;
#pragma unroll
        for (int c4 = 0; c4 < 4; c4++) {
          float4 k4 = tile4[c4][ty + dy][tx + dx];
          acc += q[c4].x * k4.x; acc += q[c4].y * k4.y;
          acc += q[c4].z * k4.z; acc += q[c4].w * k4.w;
        }
        sim[dy * 7 + dx] += acc;
      }
  }

  // softmax over 49 (zero-padded OOB entries participate with sim=0, matching reference)
  float mx = sim[0];
#pragma unroll
  for (int p = 1; p < 49; p++) mx = fmaxf(mx, sim[p]);
  float ssum = 0.f;
#pragma unroll
  for (int p = 0; p < 49; p++) { sim[p] = __expf(sim[p] - mx); ssum += sim[p]; }
  float inv = 1.0f / ssum;
#pragma unroll
  for (int p = 0; p < 49; p++) sim[p] *= inv;

#pragma unroll 1
  for (int ch = 0; ch < 128; ch += 16) {
    __syncthreads();
    stage(value, ch);
    __syncthreads();
    float4 acc[4];
#pragma unroll
    for (int c4 = 0; c4 < 4; c4++) acc[c4] = {0.f, 0.f, 0.f, 0.f};
#pragma unroll
    for (int dy = 0; dy < 7; dy++)
#pragma unroll
      for (int dx = 0; dx < 7; dx++) {
        float wgt = sim[dy * 7 + dx];
#pragma unroll
        for (int c4 = 0; c4 < 4; c4++) {
          float4 v4 = tile4[c4][ty + dy][tx + dx];
          acc[c4].x += wgt * v4.x; acc[c4].y += wgt * v4.y;
          acc[c4].z += wgt * v4.z; acc[c4].w += wgt * v4.w;
        }
      }
#pragma unroll
    for (int c4 = 0; c4 < 4; c4++) {
      float* cp = ctxb + (size_t)(ch + c4 * 4) * HWs + n;
      cp[0] = acc[c4].x; cp[HWs] = acc[c4].y; cp[2 * HWs] = acc[c4].z; cp[3 * HWs] = acc[c4].w;
    }
  }
}

extern "C" void kernel_launch(void* const* d_in, const int* in_sizes, int n_in,
                              void* d_out, int out_size, void* d_ws, size_t ws_size,
                              hipStream_t stream) {
  (void)in_sizes; (void)n_in; (void)out_size; (void)ws_size;
  const float* x      = (const float*)d_in[0];
  const float* fk_w1  = (const float*)d_in[1];
  const float* fk_b1  = (const float*)d_in[2];
  const float* fk_bn1 = (const float*)d_in[3];
  const float* fk_w2  = (const float*)d_in[4];
  const float* fk_b2  = (const float*)d_in[5];
  const float* fk_bn2 = (const float*)d_in[6];
  const float* fq_w1  = (const float*)d_in[7];
  const float* fq_b1  = (const float*)d_in[8];
  const float* fq_bn1 = (const float*)d_in[9];
  const float* fq_w2  = (const float*)d_in[10];
  const float* fq_b2  = (const float*)d_in[11];
  const float* fq_bn2 = (const float*)d_in[12];
  const float* fv_w   = (const float*)d_in[13];
  const float* fv_b   = (const float*)d_in[14];
  const float* W_w    = (const float*)d_in[15];
  const float* W_b    = (const float*)d_in[16];
  float* ws  = (float*)d_ws;
  float* out = (float*)d_out;

  prep_kernel<<<dim3(291), dim3(256), 0, stream>>>(
      fk_w1, fk_b1, fk_bn1, fk_w2, fk_b2, fk_bn2,
      fq_w1, fq_b1, fq_bn1, fq_w2, fq_b2, fq_bn2, fv_w, fv_b, W_b, ws);

  // stage1: x(256) -> [value(128) | k1(64) | q1(64)] ; relu on rows >=128
  gemm_f32<<<dim3(144, 4, 2), dim3(256), 0, stream>>>(
      ws + OFF_WCAT1, x, x, ws + OFF_ST1, ws + OFF_S1, ws + OFF_T1,
      256, 256, 1 << 30, 128, (long)256 * HWs, (long)256 * HWs);

  // stage2: k1 -> key (rows 0-63), q1 -> query (rows 64-127); relu all
  gemm_f32<<<dim3(144, 2, 2), dim3(256), 0, stream>>>(
      ws + OFF_WCAT2, ws + OFF_ST1 + (size_t)128 * HWs, ws + OFF_ST1 + (size_t)192 * HWs,
      ws + OFF_ST2, ws + OFF_S2, ws + OFF_T2,
      128, 64, 64, 0, (long)256 * HWs, (long)128 * HWs);

  // attention: writes context into st1 rows 128..255 (aliasing dead k1/q1)
  attn_kernel<<<dim3(12, 12, 2), dim3(64), 0, stream>>>(ws + OFF_ST1, ws + OFF_ST2);

  // final: context(128) -> out(256), bias only
  gemm_f32<<<dim3(144, 4, 2), dim3(256), 0, stream>>>(
      W_w, ws + OFF_ST1 + (size_t)128 * HWs, ws + OFF_ST1 + (size_t)128 * HWs,
      out, ws + OFF_S3, ws + OFF_T3,
      256, 128, 1 << 30, 256, (long)256 * HWs, (long)256 * HWs);
}

// Round 2
// 210.392 us; speedup vs baseline: 1.2494x; 1.2494x over previous
//
#include <hip/hip_runtime.h>
#include <hip/hip_bf16.h>

#define HH 96
#define WW 96
#define HWs 9216
#define NB 2
#define BN_EPS 1e-5f

// ---- workspace layout (float offsets) ----
#define OFF_WCAT1 0                       // 256x256
#define OFF_WCAT2 65536                   // 128x64
#define OFF_S1    73728                   // 256
#define OFF_T1    73984                   // 256
#define OFF_S2    74240                   // 128
#define OFF_T2    74368                   // 128
#define OFF_S3    74496                   // 256
#define OFF_T3    74752                   // 256
#define OFF_ST1   75008                   // [b][256][HW]: rows 0-127 = value, 128-191 = k1, 192-255 = q1
#define OFF_ST2   (OFF_ST1 + NB*256*HWs)  // [b][128][HW]: rows 0-63 = key, 64-127 = query
// context aliases st1 rows 128..255 (k1/q1 dead after stage2)

// ---------------- prep: fold BN into (s,t) epilogues, concat weights ----------------
__global__ __launch_bounds__(256) void prep_kernel(
    const float* __restrict__ fk_w1, const float* __restrict__ fk_b1, const float* __restrict__ fk_bn1,
    const float* __restrict__ fk_w2, const float* __restrict__ fk_b2, const float* __restrict__ fk_bn2,
    const float* __restrict__ fq_w1, const float* __restrict__ fq_b1, const float* __restrict__ fq_bn1,
    const float* __restrict__ fq_w2, const float* __restrict__ fq_b2, const float* __restrict__ fq_bn2,
    const float* __restrict__ fv_w,  const float* __restrict__ fv_b,
    const float* __restrict__ W_b,   float* __restrict__ ws)
{
  int i = blockIdx.x * 256 + threadIdx.x;
  if (i < 65536) {
    int o = i >> 8, c = i & 255;
    float v;
    if (o < 128)      v = fv_w[o * 256 + c];
    else if (o < 192) v = fk_w1[(o - 128) * 256 + c];
    else              v = fq_w1[(o - 192) * 256 + c];
    ws[OFF_WCAT1 + i] = v;
  } else if (i < 73728) {
    int j = i - 65536; int o = j >> 6, c = j & 63;
    ws[OFF_WCAT2 + j] = (o < 64) ? fk_w2[o * 64 + c] : fq_w2[(o - 64) * 64 + c];
  } else if (i < 73984) {
    int o = i - 73728;
    float s, t;
    if (o < 128) { s = 1.0f; t = fv_b[o]; }
    else if (o < 192) {
      int j = o - 128;
      float g = fk_bn1[j], be = fk_bn1[64 + j], m = fk_bn1[128 + j], v = fk_bn1[192 + j];
      s = g * rsqrtf(v + BN_EPS); t = (fk_b1[j] - m) * s + be;
    } else {
      int j = o - 192;
      float g = fq_bn1[j], be = fq_bn1[64 + j], m = fq_bn1[128 + j], v = fq_bn1[192 + j];
      s = g * rsqrtf(v + BN_EPS); t = (fq_b1[j] - m) * s + be;
    }
    ws[OFF_S1 + o] = s; ws[OFF_T1 + o] = t;
  } else if (i < 74112) {
    int o = i - 73984;
    float s, t;
    if (o < 64) {
      float g = fk_bn2[o], be = fk_bn2[64 + o], m = fk_bn2[128 + o], v = fk_bn2[192 + o];
      s = g * rsqrtf(v + BN_EPS); t = (fk_b2[o] - m) * s + be;
    } else {
      int j = o - 64;
      float g = fq_bn2[j], be = fq_bn2[64 + j], m = fq_bn2[128 + j], v = fq_bn2[192 + j];
      s = g * rsqrtf(v + BN_EPS); t = (fq_b2[j] - m) * s + be;
    }
    ws[OFF_S2 + o] = s; ws[OFF_T2 + o] = t;
  } else if (i < 74368) {
    int o = i - 74112;
    ws[OFF_S3 + o] = 1.0f; ws[OFF_T3 + o] = W_b[o];
  }
}

// ---------------- generic f32 GEMM: C[o][n] = sum_k A[o][k]*B[k][n], epilogue y=acc*s+t (+relu) ----------------
__global__ __launch_bounds__(256) void gemm_f32(
    const float* __restrict__ A, const float* __restrict__ B0, const float* __restrict__ B1,
    float* __restrict__ C, const float* __restrict__ S, const float* __restrict__ T,
    int M, int K, int m_split, int relu_start, long bStrideB, long bStrideC)
{
  __shared__ float As[16][68];
  __shared__ float Bs[16][68];
  const int tid = threadIdx.x;
  const int nb = blockIdx.x, mb = blockIdx.y, bb = blockIdx.z;
  const int m0 = mb * 64, n0 = nb * 64;
  const float* B = ((m0 >= m_split) ? B1 : B0) + (size_t)bb * bStrideB;
  float* Cb = C + (size_t)bb * bStrideC;

  float acc[4][4] = {{0.f}};
  const int la_m = tid >> 2, la_k = (tid & 3) * 4;
  const int lb_k = tid >> 4, lb_n = (tid & 15) * 4;
  const int tm = (tid >> 4) * 4, tn = (tid & 15) * 4;

  for (int k0 = 0; k0 < K; k0 += 16) {
    float4 a4 = *reinterpret_cast<const float4*>(A + (size_t)(m0 + la_m) * K + k0 + la_k);
    float4 b4 = *reinterpret_cast<const float4*>(B + (size_t)(k0 + lb_k) * HWs + n0 + lb_n);
    As[la_k + 0][la_m] = a4.x; As[la_k + 1][la_m] = a4.y;
    As[la_k + 2][la_m] = a4.z; As[la_k + 3][la_m] = a4.w;
    *reinterpret_cast<float4*>(&Bs[lb_k][lb_n]) = b4;
    __syncthreads();
#pragma unroll
    for (int k = 0; k < 16; k++) {
      float4 av = *reinterpret_cast<const float4*>(&As[k][tm]);
      float4 bv = *reinterpret_cast<const float4*>(&Bs[k][tn]);
      float a_[4] = {av.x, av.y, av.z, av.w};
      float b_[4] = {bv.x, bv.y, bv.z, bv.w};
#pragma unroll
      for (int i = 0; i < 4; i++)
#pragma unroll
        for (int j = 0; j < 4; j++) acc[i][j] += a_[i] * b_[j];
    }
    __syncthreads();
  }
#pragma unroll
  for (int i = 0; i < 4; i++) {
    int o = m0 + tm + i;
    float s = S[o], t = T[o];
    bool relu = (o >= relu_start);
    float4 r;
    r.x = acc[i][0] * s + t; r.y = acc[i][1] * s + t;
    r.z = acc[i][2] * s + t; r.w = acc[i][3] * s + t;
    if (relu) {
      r.x = fmaxf(r.x, 0.f); r.y = fmaxf(r.y, 0.f);
      r.z = fmaxf(r.z, 0.f); r.w = fmaxf(r.w, 0.f);
    }
    *reinterpret_cast<float4*>(Cb + (size_t)o * HWs + n0 + tn) = r;
  }
}

// ---------------- attention: 8x8 pixel tile, 256 threads (4 waves), channel-split ----------------
// Wave w: QK over key channels [16w,16w+16); partial sims reduced in LDS; softmax
// computed redundantly per-thread; PV: per 16-ch value stage, wave w owns c4 group w.
__global__ __launch_bounds__(256) void attn_kernel(const float* __restrict__ st1,
                                                   const float* __restrict__ st2)
{
  __shared__ float4 kt[16][14][15];   // 53,760 B: key (16 c4 groups) / value stage (4 groups)
  __shared__ float sim_s[64][53];     // 13,568 B: stride 53 -> 2-way bank alias (free)
  const int tid = threadIdx.x;
  const int w = tid >> 6;             // wave 0..3
  const int px = tid & 63;
  const int tx = px & 7, ty = px >> 3;
  const int bb = blockIdx.z;
  const int x0 = blockIdx.x * 8, y0 = blockIdx.y * 8;
  const float* key   = st2 + (size_t)bb * 128 * HWs;
  const float* query = key + (size_t)64 * HWs;
  const float* value = st1 + (size_t)bb * 256 * HWs;        // rows 0..127
  float* ctxb = const_cast<float*>(st1) + (size_t)bb * 256 * HWs + (size_t)128 * HWs;
  const int n = (y0 + ty) * WW + (x0 + tx);

  auto stage = [&](const float* __restrict__ src, int cbase, int ngroups) {
    const int total = ngroups * 196;
    for (int idx = tid; idx < total; idx += 256) {
      int c4 = idx / 196;
      int rem = idx - c4 * 196;
      int yy = rem / 14;
      int xx = rem - yy * 14;
      int gy = y0 - 3 + yy, gx = x0 - 3 + xx;
      float4 v = {0.f, 0.f, 0.f, 0.f};
      if ((unsigned)gy < (unsigned)HH && (unsigned)gx < (unsigned)WW) {
        const float* p = src + (size_t)(cbase + c4 * 4) * HWs + gy * WW + gx;
        v.x = p[0]; v.y = p[HWs]; v.z = p[2 * HWs]; v.w = p[3 * HWs];
      }
      kt[c4][yy][xx] = v;
    }
  };

  // ---- QK: stage all 64 key channels once ----
  stage(st2 + (size_t)bb * 128 * HWs, 0, 16);
  (void)key;
  __syncthreads();

  float4 q[4];
#pragma unroll
  for (int c = 0; c < 4; c++) {
    const float* qp = query + (size_t)(16 * w + 4 * c) * HWs + n;
    q[c].x = qp[0]; q[c].y = qp[HWs]; q[c].z = qp[2 * HWs]; q[c].w = qp[3 * HWs];
  }

  float part[49];
#pragma unroll
  for (int dy = 0; dy < 7; dy++)
#pragma unroll
    for (int dx = 0; dx < 7; dx++) {
      float acc = 0.f;
#pragma unroll
      for (int c = 0; c < 4; c++) {
        float4 k4 = kt[4 * w + c][ty + dy][tx + dx];
        acc += q[c].x * k4.x; acc += q[c].y * k4.y;
        acc += q[c].z * k4.z; acc += q[c].w * k4.w;
      }
      part[dy * 7 + dx] = acc;
    }

  // ---- cross-wave reduction (deterministic, sequential) ----
  if (w == 0) {
#pragma unroll
    for (int p = 0; p < 49; p++) sim_s[px][p] = part[p];
  }
  __syncthreads();
  if (w == 1) {
#pragma unroll
    for (int p = 0; p < 49; p++) sim_s[px][p] += part[p];
  }
  __syncthreads();
  if (w == 2) {
#pragma unroll
    for (int p = 0; p < 49; p++) sim_s[px][p] += part[p];
  }
  __syncthreads();
  if (w == 3) {
#pragma unroll
    for (int p = 0; p < 49; p++) sim_s[px][p] += part[p];
  }
  __syncthreads();

  // ---- softmax: every thread computes its pixel's softmax in registers ----
  float sim[49];
#pragma unroll
  for (int p = 0; p < 49; p++) sim[p] = sim_s[px][p];
  float mx = sim[0];
#pragma unroll
  for (int p = 1; p < 49; p++) mx = fmaxf(mx, sim[p]);
  float ssum = 0.f;
#pragma unroll
  for (int p = 0; p < 49; p++) { sim[p] = __expf(sim[p] - mx); ssum += sim[p]; }
  float inv = 1.0f / ssum;
#pragma unroll
  for (int p = 0; p < 49; p++) sim[p] *= inv;

  // ---- PV: 8 stages of 16 value channels; wave w owns c4 group w ----
#pragma unroll 1
  for (int vs = 0; vs < 8; ++vs) {
    __syncthreads();               // previous-stage kt reads (or QK reads) complete
    stage(value, vs * 16, 4);
    __syncthreads();
    float4 acc = {0.f, 0.f, 0.f, 0.f};
#pragma unroll
    for (int dy = 0; dy < 7; dy++)
#pragma unroll
      for (int dx = 0; dx < 7; dx++) {
        float f = sim[dy * 7 + dx];
        float4 v4 = kt[w][ty + dy][tx + dx];
        acc.x += f * v4.x; acc.y += f * v4.y;
        acc.z += f * v4.z; acc.w += f * v4.w;
      }
    float* cp = ctxb + (size_t)(vs * 16 + 4 * w) * HWs + n;
    cp[0] = acc.x; cp[HWs] = acc.y; cp[2 * HWs] = acc.z; cp[3 * HWs] = acc.w;
  }
}

extern "C" void kernel_launch(void* const* d_in, const int* in_sizes, int n_in,
                              void* d_out, int out_size, void* d_ws, size_t ws_size,
                              hipStream_t stream) {
  (void)in_sizes; (void)n_in; (void)out_size; (void)ws_size;
  const float* x      = (const float*)d_in[0];
  const float* fk_w1  = (const float*)d_in[1];
  const float* fk_b1  = (const float*)d_in[2];
  const float* fk_bn1 = (const float*)d_in[3];
  const float* fk_w2  = (const float*)d_in[4];
  const float* fk_b2  = (const float*)d_in[5];
  const float* fk_bn2 = (const float*)d_in[6];
  const float* fq_w1  = (const float*)d_in[7];
  const float* fq_b1  = (const float*)d_in[8];
  const float* fq_bn1 = (const float*)d_in[9];
  const float* fq_w2  = (const float*)d_in[10];
  const float* fq_b2  = (const float*)d_in[11];
  const float* fq_bn2 = (const float*)d_in[12];
  const float* fv_w   = (const float*)d_in[13];
  const float* fv_b   = (const float*)d_in[14];
  const float* W_w    = (const float*)d_in[15];
  const float* W_b    = (const float*)d_in[16];
  float* ws  = (float*)d_ws;
  float* out = (float*)d_out;

  prep_kernel<<<dim3(291), dim3(256), 0, stream>>>(
      fk_w1, fk_b1, fk_bn1, fk_w2, fk_b2, fk_bn2,
      fq_w1, fq_b1, fq_bn1, fq_w2, fq_b2, fq_bn2, fv_w, fv_b, W_b, ws);

  // stage1: x(256) -> [value(128) | k1(64) | q1(64)] ; relu on rows >=128
  gemm_f32<<<dim3(144, 4, 2), dim3(256), 0, stream>>>(
      ws + OFF_WCAT1, x, x, ws + OFF_ST1, ws + OFF_S1, ws + OFF_T1,
      256, 256, 1 << 30, 128, (long)256 * HWs, (long)256 * HWs);

  // stage2: k1 -> key (rows 0-63), q1 -> query (rows 64-127); relu all
  gemm_f32<<<dim3(144, 2, 2), dim3(256), 0, stream>>>(
      ws + OFF_WCAT2, ws + OFF_ST1 + (size_t)128 * HWs, ws + OFF_ST1 + (size_t)192 * HWs,
      ws + OFF_ST2, ws + OFF_S2, ws + OFF_T2,
      128, 64, 64, 0, (long)256 * HWs, (long)128 * HWs);

  // attention: writes context into st1 rows 128..255 (aliasing dead k1/q1)
  attn_kernel<<<dim3(12, 12, 2), dim3(256), 0, stream>>>(ws + OFF_ST1, ws + OFF_ST2);

  // final: context(128) -> out(256), bias only
  gemm_f32<<<dim3(144, 4, 2), dim3(256), 0, stream>>>(
      W_w, ws + OFF_ST1 + (size_t)128 * HWs, ws + OFF_ST1 + (size_t)128 * HWs,
      out, ws + OFF_S3, ws + OFF_T3,
      256, 128, 1 << 30, 256, (long)256 * HWs, (long)256 * HWs);
}

// Round 3
// 158.275 us; speedup vs baseline: 1.6608x; 1.3293x over previous
//
#include <hip/hip_runtime.h>
#include <hip/hip_bf16.h>

typedef _Float16 f16;
typedef _Float16 f16x8 __attribute__((ext_vector_type(8)));
typedef float f32x4 __attribute__((ext_vector_type(4)));

#define HH 96
#define WW 96
#define HWs 9216
#define BN_EPS 1e-5f

// ---- workspace layout (byte offsets) ----
#define OFF_XT   0u            // [b][9216][256] f16  (x NHWC)          9,437,184
#define OFF_ACT1 9437184u      // [b][9216][256] f16: ch0-127 value, 128-191 k1, 192-255 q1
#define OFF_ACT2 18874368u     // [b][9216][128] f16: ch0-63 key, 64-127 query
#define OFF_CTX  23592960u     // [b][9216][128] f16
#define OFF_W1   28311552u     // [256][256] f16
#define OFF_W2   28442624u     // [128][64] f16
#define OFF_W3   28459008u     // [256][128] f16
#define OFF_ST   28524544u     // f32: s1[256] t1[256] s2[128] t2[128] t3[256]

// ---------------- prep ----------------
__global__ __launch_bounds__(256) void prep_kernel(
    const float* __restrict__ fk_w1, const float* __restrict__ fk_b1, const float* __restrict__ fk_bn1,
    const float* __restrict__ fk_w2, const float* __restrict__ fk_b2, const float* __restrict__ fk_bn2,
    const float* __restrict__ fq_w1, const float* __restrict__ fq_b1, const float* __restrict__ fq_bn1,
    const float* __restrict__ fq_w2, const float* __restrict__ fq_b2, const float* __restrict__ fq_bn2,
    const float* __restrict__ fv_w,  const float* __restrict__ fv_b,
    const float* __restrict__ W_w,   const float* __restrict__ W_b,
    char* __restrict__ wsb)
{
  f16* w1 = (f16*)(wsb + OFF_W1);
  f16* w2 = (f16*)(wsb + OFF_W2);
  f16* w3 = (f16*)(wsb + OFF_W3);
  float* st = (float*)(wsb + OFF_ST);
  int i = blockIdx.x * 256 + threadIdx.x;
  if (i < 65536) {
    int o = i >> 8, c = i & 255;
    float v;
    if (o < 128)      v = fv_w[o * 256 + c];
    else if (o < 192) v = fk_w1[(o - 128) * 256 + c];
    else              v = fq_w1[(o - 192) * 256 + c];
    w1[i] = (f16)v;
  } else if (i < 73728) {
    int j = i - 65536; int o = j >> 6, c = j & 63;
    w2[j] = (f16)((o < 64) ? fk_w2[o * 64 + c] : fq_w2[(o - 64) * 64 + c]);
  } else if (i < 106496) {
    int j = i - 73728;
    w3[j] = (f16)W_w[j];
  } else if (i < 106752) {
    int o = i - 106496;
    float s, t;
    if (o < 128) { s = 1.0f; t = fv_b[o]; }
    else if (o < 192) {
      int j = o - 128;
      float g = fk_bn1[j], be = fk_bn1[64 + j], m = fk_bn1[128 + j], v = fk_bn1[192 + j];
      s = g * rsqrtf(v + BN_EPS); t = (fk_b1[j] - m) * s + be;
    } else {
      int j = o - 192;
      float g = fq_bn1[j], be = fq_bn1[64 + j], m = fq_bn1[128 + j], v = fq_bn1[192 + j];
      s = g * rsqrtf(v + BN_EPS); t = (fq_b1[j] - m) * s + be;
    }
    st[o] = s; st[256 + o] = t;
  } else if (i < 106880) {
    int o = i - 106752;
    float s, t;
    if (o < 64) {
      float g = fk_bn2[o], be = fk_bn2[64 + o], m = fk_bn2[128 + o], v = fk_bn2[192 + o];
      s = g * rsqrtf(v + BN_EPS); t = (fk_b2[o] - m) * s + be;
    } else {
      int j = o - 64;
      float g = fq_bn2[j], be = fq_bn2[64 + j], m = fq_bn2[128 + j], v = fq_bn2[192 + j];
      s = g * rsqrtf(v + BN_EPS); t = (fq_b2[j] - m) * s + be;
    }
    st[512 + o] = s; st[640 + o] = t;
  } else if (i < 107136) {
    int o = i - 106880;
    st[768 + o] = W_b[o];
  }
}

// ---------------- transpose x: NCHW f32 -> NHWC f16 ----------------
__global__ __launch_bounds__(256) void transpose_in(const float* __restrict__ x, f16* __restrict__ xT)
{
  __shared__ float lds[64 * 65];
  const int t = threadIdx.x;
  const int p0 = blockIdx.x * 64, c0 = blockIdx.y * 64, bb = blockIdx.z;
#pragma unroll
  for (int pass = 0; pass < 16; ++pass) {
    int ch = pass * 4 + (t >> 6), px = t & 63;
    lds[ch * 65 + px] = x[((size_t)bb * 256 + c0 + ch) * HWs + p0 + px];
  }
  __syncthreads();
#pragma unroll
  for (int pass = 0; pass < 2; ++pass) {
    int pl = pass * 32 + (t >> 3), cs = t & 7;
    f16x8 v;
#pragma unroll
    for (int j = 0; j < 8; j++) v[j] = (f16)lds[(cs * 8 + j) * 65 + pl];
    *(f16x8*)&xT[((size_t)bb * HWs + p0 + pl) * 256 + c0 + cs * 8] = v;
  }
}

// ---------------- MFMA GEMM: 128 pixels x 128 couts per block, 4 waves 2x2 ----------------
// C_nhwc[p][cout] = epilogue( sum_k Aact[p][ka0+k] * W[cout][k] )
template<int KTOT, bool NCHW_OUT>
__global__ __launch_bounds__(256) void gemm128(
    const f16* __restrict__ Aact, int lda, int ka0,
    const f16* __restrict__ W,
    f16* __restrict__ Cout, int ldc, int cbase,
    float* __restrict__ out_nchw,
    const float* __restrict__ S, const float* __restrict__ T, int relu_start)
{
  __shared__ f16 As[128 * 40];
  __shared__ f16 Bs[128 * 40];
  const int tid = threadIdx.x;
  const int l = tid & 63, w = tid >> 6;
  const int bb = blockIdx.z;
  const int p0 = blockIdx.x * 128, n0 = blockIdx.y * 128;
  const f16* Ab = Aact + (size_t)bb * HWs * lda;
  f32x4 acc[4][4];
#pragma unroll
  for (int i = 0; i < 4; i++)
#pragma unroll
    for (int j = 0; j < 4; j++) acc[i][j] = (f32x4){0.f, 0.f, 0.f, 0.f};
  const int wm = (w >> 1) * 64, wn = (w & 1) * 64;
  const int lrow = l & 15, lk = (l >> 4) * 8;
#pragma unroll 1
  for (int ks = 0; ks < KTOT / 32; ks++) {
#pragma unroll
    for (int it = 0; it < 2; it++) {
      int tt = it * 256 + tid;
      int row = tt >> 2, seg = tt & 3;
      *(f16x8*)&As[row * 40 + seg * 8] =
          *(const f16x8*)&Ab[(size_t)(p0 + row) * lda + ka0 + ks * 32 + seg * 8];
      *(f16x8*)&Bs[row * 40 + seg * 8] =
          *(const f16x8*)&W[(size_t)(n0 + row) * KTOT + ks * 32 + seg * 8];
    }
    __syncthreads();
    f16x8 a[4], b[4];
#pragma unroll
    for (int mi = 0; mi < 4; mi++) a[mi] = *(const f16x8*)&As[(wm + mi * 16 + lrow) * 40 + lk];
#pragma unroll
    for (int ni = 0; ni < 4; ni++) b[ni] = *(const f16x8*)&Bs[(wn + ni * 16 + lrow) * 40 + lk];
#pragma unroll
    for (int mi = 0; mi < 4; mi++)
#pragma unroll
      for (int ni = 0; ni < 4; ni++)
        acc[mi][ni] = __builtin_amdgcn_mfma_f32_16x16x32_f16(a[mi], b[ni], acc[mi][ni], 0, 0, 0);
    __syncthreads();
  }
#pragma unroll
  for (int mi = 0; mi < 4; mi++)
#pragma unroll
    for (int ni = 0; ni < 4; ni++) {
      int coutl = n0 + wn + ni * 16 + lrow;
      int pb = p0 + wm + mi * 16 + (l >> 4) * 4;
      if (NCHW_OUT) {
        float t = T[coutl];
        float4 o;
        o.x = acc[mi][ni][0] + t; o.y = acc[mi][ni][1] + t;
        o.z = acc[mi][ni][2] + t; o.w = acc[mi][ni][3] + t;
        *(float4*)&out_nchw[((size_t)bb * 256 + coutl) * HWs + pb] = o;
      } else {
        float s = S[coutl], t = T[coutl];
        bool rl = coutl >= relu_start;
#pragma unroll
        for (int r = 0; r < 4; r++) {
          float v = acc[mi][ni][r] * s + t;
          if (rl) v = fmaxf(v, 0.f);
          Cout[((size_t)bb * HWs + pb + r) * ldc + cbase + coutl] = (f16)v;
        }
      }
    }
}

// ---------------- stage2 GEMM: 256 pixels x 64 couts, 4 waves stacked in M ----------------
__global__ __launch_bounds__(256) void gemm_s2(
    const f16* __restrict__ Aact, int ka0,
    const f16* __restrict__ W,
    f16* __restrict__ Cout, int cbase,
    const float* __restrict__ S, const float* __restrict__ T)
{
  __shared__ f16 As[256 * 40];
  __shared__ f16 Bs[64 * 40];
  const int tid = threadIdx.x;
  const int l = tid & 63, w = tid >> 6;
  const int bb = blockIdx.z;
  const int p0 = blockIdx.x * 256;
  const f16* Ab = Aact + (size_t)bb * HWs * 256;
  f32x4 acc[4][4];
#pragma unroll
  for (int i = 0; i < 4; i++)
#pragma unroll
    for (int j = 0; j < 4; j++) acc[i][j] = (f32x4){0.f, 0.f, 0.f, 0.f};
  const int wm = w * 64;
  const int lrow = l & 15, lk = (l >> 4) * 8;
#pragma unroll 1
  for (int ks = 0; ks < 2; ks++) {
#pragma unroll
    for (int it = 0; it < 4; it++) {
      int tt = it * 256 + tid;
      int row = tt >> 2, seg = tt & 3;
      *(f16x8*)&As[row * 40 + seg * 8] =
          *(const f16x8*)&Ab[(size_t)(p0 + row) * 256 + ka0 + ks * 32 + seg * 8];
    }
    {
      int row = tid >> 2, seg = tid & 3;
      *(f16x8*)&Bs[row * 40 + seg * 8] =
          *(const f16x8*)&W[(size_t)row * 64 + ks * 32 + seg * 8];
    }
    __syncthreads();
    f16x8 a[4], b[4];
#pragma unroll
    for (int mi = 0; mi < 4; mi++) a[mi] = *(const f16x8*)&As[(wm + mi * 16 + lrow) * 40 + lk];
#pragma unroll
    for (int ni = 0; ni < 4; ni++) b[ni] = *(const f16x8*)&Bs[(ni * 16 + lrow) * 40 + lk];
#pragma unroll
    for (int mi = 0; mi < 4; mi++)
#pragma unroll
      for (int ni = 0; ni < 4; ni++)
        acc[mi][ni] = __builtin_amdgcn_mfma_f32_16x16x32_f16(a[mi], b[ni], acc[mi][ni], 0, 0, 0);
    __syncthreads();
  }
#pragma unroll
  for (int mi = 0; mi < 4; mi++)
#pragma unroll
    for (int ni = 0; ni < 4; ni++) {
      int coutl = ni * 16 + lrow;
      int pb = p0 + wm + mi * 16 + (l >> 4) * 4;
      float s = S[coutl], t = T[coutl];
#pragma unroll
      for (int r = 0; r < 4; r++) {
        float v = fmaxf(acc[mi][ni][r] * s + t, 0.f);
        Cout[((size_t)bb * HWs + pb + r) * 128 + cbase + coutl] = (f16)v;
      }
    }
}

// ---------------- attention: 8x8 pixel tile, MFMA QK + VALU PV ----------------
__global__ __launch_bounds__(256) void attn_kernel(const f16* __restrict__ act1,
                                                   const f16* __restrict__ act2,
                                                   f16* __restrict__ ctx)
{
  __shared__ float Ps[64 * 52];      // 13,312 B
  __shared__ f16 buf[208 * 136];     // 56,576 B: phase1 Qs[64*72]+Ks[208*72]; phase2 Vs[208*136]
  const int tid = threadIdx.x;
  const int l = tid & 63, w = tid >> 6;
  const int bb = blockIdx.z;
  const int x0 = blockIdx.x * 8, y0 = blockIdx.y * 8;
  const f16* a2 = act2 + (size_t)bb * HWs * 128;
  const f16* a1 = act1 + (size_t)bb * HWs * 256;
  f16* ctxb = ctx + (size_t)bb * HWs * 128;
  f16* Qs = buf;
  f16* Ks = buf + 64 * 72;

  // stage Q (query = act2 ch 64..127)
#pragma unroll
  for (int it = 0; it < 2; it++) {
    int t = it * 256 + tid;
    int q = t >> 3, seg = t & 7;
    int gp = (y0 + (q >> 3)) * WW + x0 + (q & 7);
    *(f16x8*)&Qs[q * 72 + seg * 8] = *(const f16x8*)&a2[(size_t)gp * 128 + 64 + seg * 8];
  }
  // stage K (key = act2 ch 0..63), 208 halo rows, zero OOB
  for (int t = tid; t < 1664; t += 256) {
    int kk = t >> 3, seg = t & 7;
    int ky = (kk * 4682) >> 16, kx = kk - 14 * ky;
    int gy = y0 - 3 + ky, gx = x0 - 3 + kx;
    f16x8 v = {(f16)0, (f16)0, (f16)0, (f16)0, (f16)0, (f16)0, (f16)0, (f16)0};
    if (kk < 196 && (unsigned)gy < (unsigned)HH && (unsigned)gx < (unsigned)WW)
      v = *(const f16x8*)&a2[((size_t)(gy * WW + gx)) * 128 + seg * 8];
    *(f16x8*)&Ks[kk * 72 + seg * 8] = v;
  }
  __syncthreads();

  // QK: wave w -> q-rows 16w..16w+15, 13 col-frags, K=64 in 2 steps
  f32x4 sc[13];
#pragma unroll
  for (int nj = 0; nj < 13; nj++) sc[nj] = (f32x4){0.f, 0.f, 0.f, 0.f};
  const int lrow = l & 15, lk = (l >> 4) * 8;
#pragma unroll
  for (int ks = 0; ks < 2; ks++) {
    f16x8 aq = *(const f16x8*)&Qs[(w * 16 + lrow) * 72 + ks * 32 + lk];
#pragma unroll
    for (int nj = 0; nj < 13; nj++) {
      f16x8 bk = *(const f16x8*)&Ks[(nj * 16 + lrow) * 72 + ks * 32 + lk];
      sc[nj] = __builtin_amdgcn_mfma_f32_16x16x32_f16(aq, bk, sc[nj], 0, 0, 0);
    }
  }
  // mask non-window cols (image-OOB stays 0 via zero-staged K = reference semantics)
  const int r0 = w * 16 + (l >> 4) * 4;
#pragma unroll
  for (int nj = 0; nj < 13; nj++) {
    int c = nj * 16 + lrow;
    int ky = (c * 4682) >> 16, kx = c - 14 * ky;
#pragma unroll
    for (int r = 0; r < 4; r++) {
      int qy = (r0 + r) >> 3, qx = (r0 + r) & 7;
      bool valid = ((unsigned)(ky - qy) < 7u) && ((unsigned)(kx - qx) < 7u);
      if (!valid) sc[nj][r] = -1e30f;
    }
  }
  // softmax per q-row (row held across 16-lane group + 13 frags)
  float mx[4], sm[4], inv[4];
#pragma unroll
  for (int r = 0; r < 4; r++) {
    mx[r] = -1e30f;
#pragma unroll
    for (int nj = 0; nj < 13; nj++) mx[r] = fmaxf(mx[r], sc[nj][r]);
  }
#pragma unroll
  for (int off = 1; off < 16; off <<= 1)
#pragma unroll
    for (int r = 0; r < 4; r++) mx[r] = fmaxf(mx[r], __shfl_xor(mx[r], off));
#pragma unroll
  for (int r = 0; r < 4; r++) sm[r] = 0.f;
#pragma unroll
  for (int nj = 0; nj < 13; nj++)
#pragma unroll
    for (int r = 0; r < 4; r++) {
      float e = __expf(sc[nj][r] - mx[r]);
      sc[nj][r] = e; sm[r] += e;
    }
#pragma unroll
  for (int off = 1; off < 16; off <<= 1)
#pragma unroll
    for (int r = 0; r < 4; r++) sm[r] += __shfl_xor(sm[r], off);
#pragma unroll
  for (int r = 0; r < 4; r++) inv[r] = 1.0f / sm[r];
  // scatter valid probs into Ps[q][49]
#pragma unroll
  for (int nj = 0; nj < 13; nj++) {
    int c = nj * 16 + lrow;
    int ky = (c * 4682) >> 16, kx = c - 14 * ky;
#pragma unroll
    for (int r = 0; r < 4; r++) {
      int qy = (r0 + r) >> 3, qx = (r0 + r) & 7;
      int dy = ky - qy, dx = kx - qx;
      if (((unsigned)dy < 7u) && ((unsigned)dx < 7u))
        Ps[(r0 + r) * 52 + dy * 7 + dx] = sc[nj][r] * inv[r];
    }
  }
  __syncthreads();

  // stage V (value = act1 ch 0..127) into full buf
  f16* Vs = buf;
  for (int t = tid; t < 3328; t += 256) {
    int kk = t >> 4, seg = t & 15;
    int ky = (kk * 4682) >> 16, kx = kk - 14 * ky;
    int gy = y0 - 3 + ky, gx = x0 - 3 + kx;
    f16x8 v = {(f16)0, (f16)0, (f16)0, (f16)0, (f16)0, (f16)0, (f16)0, (f16)0};
    if (kk < 196 && (unsigned)gy < (unsigned)HH && (unsigned)gx < (unsigned)WW)
      v = *(const f16x8*)&a1[((size_t)(gy * WW + gx)) * 256 + seg * 8];
    *(f16x8*)&Vs[kk * 136 + seg * 8] = v;
  }
  __syncthreads();

  // PV: thread = (pixel q = tid>>2, 32-ch chunk), f32 accum via fma_mix
  const int q = tid >> 2;
  const int qy = q >> 3, qx = q & 7;
  const int ch0 = (tid & 3) * 32;
  float acc[32];
#pragma unroll
  for (int i = 0; i < 32; i++) acc[i] = 0.f;
#pragma unroll
  for (int dy = 0; dy < 7; dy++)
#pragma unroll
    for (int dx = 0; dx < 7; dx++) {
      float p = Ps[q * 52 + dy * 7 + dx];
      int kk = (qy + dy) * 14 + qx + dx;
      const f16* vp = &Vs[kk * 136 + ch0];
#pragma unroll
      for (int s = 0; s < 4; s++) {
        f16x8 v = *(const f16x8*)&vp[s * 8];
#pragma unroll
        for (int j = 0; j < 8; j++) acc[s * 8 + j] += (float)v[j] * p;
      }
    }
  int gp = (y0 + qy) * WW + x0 + qx;
#pragma unroll
  for (int s = 0; s < 4; s++) {
    f16x8 o;
#pragma unroll
    for (int j = 0; j < 8; j++) o[j] = (f16)acc[s * 8 + j];
    *(f16x8*)&ctxb[(size_t)gp * 128 + ch0 + s * 8] = o;
  }
}

extern "C" void kernel_launch(void* const* d_in, const int* in_sizes, int n_in,
                              void* d_out, int out_size, void* d_ws, size_t ws_size,
                              hipStream_t stream) {
  (void)in_sizes; (void)n_in; (void)out_size; (void)ws_size;
  const float* x      = (const float*)d_in[0];
  const float* fk_w1  = (const float*)d_in[1];
  const float* fk_b1  = (const float*)d_in[2];
  const float* fk_bn1 = (const float*)d_in[3];
  const float* fk_w2  = (const float*)d_in[4];
  const float* fk_b2  = (const float*)d_in[5];
  const float* fk_bn2 = (const float*)d_in[6];
  const float* fq_w1  = (const float*)d_in[7];
  const float* fq_b1  = (const float*)d_in[8];
  const float* fq_bn1 = (const float*)d_in[9];
  const float* fq_w2  = (const float*)d_in[10];
  const float* fq_b2  = (const float*)d_in[11];
  const float* fq_bn2 = (const float*)d_in[12];
  const float* fv_w   = (const float*)d_in[13];
  const float* fv_b   = (const float*)d_in[14];
  const float* W_w    = (const float*)d_in[15];
  const float* W_b    = (const float*)d_in[16];
  char* wsb = (char*)d_ws;
  float* out = (float*)d_out;

  f16* xT   = (f16*)(wsb + OFF_XT);
  f16* act1 = (f16*)(wsb + OFF_ACT1);
  f16* act2 = (f16*)(wsb + OFF_ACT2);
  f16* ctx  = (f16*)(wsb + OFF_CTX);
  f16* w1   = (f16*)(wsb + OFF_W1);
  f16* w2   = (f16*)(wsb + OFF_W2);
  f16* w3   = (f16*)(wsb + OFF_W3);
  float* st = (float*)(wsb + OFF_ST);

  prep_kernel<<<dim3(419), dim3(256), 0, stream>>>(
      fk_w1, fk_b1, fk_bn1, fk_w2, fk_b2, fk_bn2,
      fq_w1, fq_b1, fq_bn1, fq_w2, fq_b2, fq_bn2, fv_w, fv_b, W_w, W_b, wsb);

  transpose_in<<<dim3(144, 4, 2), dim3(256), 0, stream>>>(x, xT);

  // stage1: xT(256) -> act1[p][256] = [value | k1 | q1]; relu on couts >=128
  gemm128<256, false><<<dim3(72, 2, 2), dim3(256), 0, stream>>>(
      xT, 256, 0, w1, act1, 256, 0, nullptr, st, st + 256, 128);

  // stage2: k1 -> key (act2 ch0-63), q1 -> query (act2 ch64-127); relu all
  gemm_s2<<<dim3(36, 1, 2), dim3(256), 0, stream>>>(
      act1, 128, w2, act2, 0, st + 512, st + 640);
  gemm_s2<<<dim3(36, 1, 2), dim3(256), 0, stream>>>(
      act1, 192, w2 + 64 * 64, act2, 64, st + 512 + 64, st + 640 + 64);

  // attention
  attn_kernel<<<dim3(12, 12, 2), dim3(256), 0, stream>>>(act1, act2, ctx);

  // final: ctx(128) -> out NCHW f32, bias only
  gemm128<128, true><<<dim3(72, 2, 2), dim3(256), 0, stream>>>(
      ctx, 128, 0, w3, nullptr, 0, 0, out, st, st + 768, 1 << 30);
}

// Round 4
// 138.817 us; speedup vs baseline: 1.8936x; 1.1402x over previous
//
#include <hip/hip_runtime.h>
#include <hip/hip_bf16.h>

typedef _Float16 f16;
typedef _Float16 f16x4 __attribute__((ext_vector_type(4)));
typedef _Float16 f16x8 __attribute__((ext_vector_type(8)));
typedef float f32x4 __attribute__((ext_vector_type(4)));

#define HH 96
#define WW 96
#define HWs 9216
#define BN_EPS 1e-5f

// ---- workspace layout (byte offsets) ----
#define OFF_ACT1 0u            // [2][9216][128] f16 : value        4,718,592
#define OFF_ACT2 4718592u      // [2][9216][128] f16 : key|query    4,718,592
#define OFF_W1   9437184u      // [256][256] f16 (value|k1|q1 weights)
#define OFF_W2   9568256u      // [128][64]  f16 (key|query weights)
#define OFF_W3   9584640u      // [256][128] f16
#define OFF_ST   9650176u      // f32: s1[256] t1[256] s2[128] t2[128] t3[256]

// ---------------- prep: fold BN, cast weights to f16 ----------------
__global__ __launch_bounds__(256) void prep_kernel(
    const float* __restrict__ fk_w1, const float* __restrict__ fk_b1, const float* __restrict__ fk_bn1,
    const float* __restrict__ fk_w2, const float* __restrict__ fk_b2, const float* __restrict__ fk_bn2,
    const float* __restrict__ fq_w1, const float* __restrict__ fq_b1, const float* __restrict__ fq_bn1,
    const float* __restrict__ fq_w2, const float* __restrict__ fq_b2, const float* __restrict__ fq_bn2,
    const float* __restrict__ fv_w,  const float* __restrict__ fv_b,
    const float* __restrict__ W_w,   const float* __restrict__ W_b,
    char* __restrict__ wsb)
{
  f16* w1 = (f16*)(wsb + OFF_W1);
  f16* w2 = (f16*)(wsb + OFF_W2);
  f16* w3 = (f16*)(wsb + OFF_W3);
  float* st = (float*)(wsb + OFF_ST);
  int i = blockIdx.x * 256 + threadIdx.x;
  if (i < 65536) {
    int o = i >> 8, c = i & 255;
    float v;
    if (o < 128)      v = fv_w[o * 256 + c];
    else if (o < 192) v = fk_w1[(o - 128) * 256 + c];
    else              v = fq_w1[(o - 192) * 256 + c];
    w1[i] = (f16)v;
  } else if (i < 73728) {
    int j = i - 65536; int o = j >> 6, c = j & 63;
    w2[j] = (f16)((o < 64) ? fk_w2[o * 64 + c] : fq_w2[(o - 64) * 64 + c]);
  } else if (i < 106496) {
    int j = i - 73728;
    w3[j] = (f16)W_w[j];
  } else if (i < 106752) {
    int o = i - 106496;
    float s, t;
    if (o < 128) { s = 1.0f; t = fv_b[o]; }
    else if (o < 192) {
      int j = o - 128;
      float g = fk_bn1[j], be = fk_bn1[64 + j], m = fk_bn1[128 + j], v = fk_bn1[192 + j];
      s = g * rsqrtf(v + BN_EPS); t = (fk_b1[j] - m) * s + be;
    } else {
      int j = o - 192;
      float g = fq_bn1[j], be = fq_bn1[64 + j], m = fq_bn1[128 + j], v = fq_bn1[192 + j];
      s = g * rsqrtf(v + BN_EPS); t = (fq_b1[j] - m) * s + be;
    }
    st[o] = s; st[256 + o] = t;
  } else if (i < 106880) {
    int o = i - 106752;
    float s, t;
    if (o < 64) {
      float g = fk_bn2[o], be = fk_bn2[64 + o], m = fk_bn2[128 + o], v = fk_bn2[192 + o];
      s = g * rsqrtf(v + BN_EPS); t = (fk_b2[o] - m) * s + be;
    } else {
      int j = o - 64;
      float g = fq_bn2[j], be = fq_bn2[64 + j], m = fq_bn2[128 + j], v = fq_bn2[192 + j];
      s = g * rsqrtf(v + BN_EPS); t = (fq_b2[j] - m) * s + be;
    }
    st[512 + o] = s; st[640 + o] = t;
  } else if (i < 107136) {
    int o = i - 106880;
    st[768 + o] = W_b[o];
  }
}

// ---------------- conv12: fused transpose + stage1 (256 couts) + stage2 (in-LDS k1/q1) ----------------
// 32-px tile, 4 waves. Wave w owns stage-1 couts [64w, 64w+64):
//   w=0,1 -> value -> act1 global; w=2 -> k1 -> LDS; w=3 -> q1 -> LDS.
// Then stage2: wave w -> (sel = w>>1 ? query : key), couts2 (w&1)*32..+32, from LDS k1/q1.
__global__ __launch_bounds__(256) void conv12(
    const float* __restrict__ x, const f16* __restrict__ W1, const f16* __restrict__ W2,
    f16* __restrict__ act1, f16* __restrict__ act2, const float* __restrict__ st)
{
  __shared__ f16 As[32 * 40];        // 2,560 B  x-tile transposed [px][k]
  __shared__ f16 Bs[256 * 40];       // 20,480 B W1 k-slice
  __shared__ f16 kqs[2][32 * 72];    // 9,216 B  k1 / q1 (relu'd)
  const int tid = threadIdx.x;
  const int l = tid & 63, w = tid >> 6;
  const int bb = blockIdx.y;
  const int p0 = blockIdx.x * 32;
  const int lrow = l & 15, lk = (l >> 4) * 8;

  f32x4 acc[2][4];
#pragma unroll
  for (int i = 0; i < 2; i++)
#pragma unroll
    for (int j = 0; j < 4; j++) acc[i][j] = (f32x4){0.f, 0.f, 0.f, 0.f};

  const int spx = tid & 31, skg = tid >> 5;   // staging: px, k-quad
#pragma unroll 1
  for (int ks = 0; ks < 8; ks++) {
    // stage A: x NCHW f32 -> As[px][k] f16 (4 strided coalesced loads -> 1 b64 write)
    f16x4 av;
#pragma unroll
    for (int j = 0; j < 4; j++)
      av[j] = (f16)x[((size_t)bb * 256 + ks * 32 + skg * 4 + j) * HWs + p0 + spx];
    *(f16x4*)&As[spx * 40 + skg * 4] = av;
    // stage B: W1 rows 0..255, k-chunk
#pragma unroll
    for (int it = 0; it < 4; it++) {
      int tt = it * 256 + tid;
      int row = tt >> 2, seg = tt & 3;
      *(f16x8*)&Bs[row * 40 + seg * 8] =
          *(const f16x8*)&W1[(size_t)row * 256 + ks * 32 + seg * 8];
    }
    __syncthreads();
    f16x8 a[2], b[4];
#pragma unroll
    for (int mi = 0; mi < 2; mi++) a[mi] = *(const f16x8*)&As[(mi * 16 + lrow) * 40 + lk];
#pragma unroll
    for (int nj = 0; nj < 4; nj++) b[nj] = *(const f16x8*)&Bs[(w * 64 + nj * 16 + lrow) * 40 + lk];
#pragma unroll
    for (int mi = 0; mi < 2; mi++)
#pragma unroll
      for (int nj = 0; nj < 4; nj++)
        acc[mi][nj] = __builtin_amdgcn_mfma_f32_16x16x32_f16(a[mi], b[nj], acc[mi][nj], 0, 0, 0);
    __syncthreads();
  }

  // stage-1 epilogue
#pragma unroll
  for (int mi = 0; mi < 2; mi++)
#pragma unroll
    for (int nj = 0; nj < 4; nj++) {
      int cout = w * 64 + nj * 16 + lrow;
      float s = st[cout], t = st[256 + cout];
#pragma unroll
      for (int r = 0; r < 4; r++) {
        int px = mi * 16 + (l >> 4) * 4 + r;
        float v = acc[mi][nj][r] * s + t;
        if (w < 2) {
          act1[((size_t)bb * HWs + p0 + px) * 128 + cout] = (f16)v;
        } else {
          kqs[w - 2][px * 72 + (nj * 16 + lrow)] = (f16)fmaxf(v, 0.f);
        }
      }
    }
  __syncthreads();

  // stage2: K=64 from LDS k1/q1
  const int sel = w >> 1, half = w & 1;
  const f16* W2s = W2 + sel * 64 * 64;
  f32x4 acc2[2][2];
#pragma unroll
  for (int i = 0; i < 2; i++)
#pragma unroll
    for (int j = 0; j < 2; j++) acc2[i][j] = (f32x4){0.f, 0.f, 0.f, 0.f};
#pragma unroll
  for (int ks = 0; ks < 2; ks++) {
    f16x8 a2[2], b2[2];
#pragma unroll
    for (int mi = 0; mi < 2; mi++)
      a2[mi] = *(const f16x8*)&kqs[sel][(mi * 16 + lrow) * 72 + ks * 32 + lk];
#pragma unroll
    for (int nj = 0; nj < 2; nj++)
      b2[nj] = *(const f16x8*)&W2s[(size_t)(half * 32 + nj * 16 + lrow) * 64 + ks * 32 + lk];
#pragma unroll
    for (int mi = 0; mi < 2; mi++)
#pragma unroll
      for (int nj = 0; nj < 2; nj++)
        acc2[mi][nj] = __builtin_amdgcn_mfma_f32_16x16x32_f16(a2[mi], b2[nj], acc2[mi][nj], 0, 0, 0);
  }
#pragma unroll
  for (int mi = 0; mi < 2; mi++)
#pragma unroll
    for (int nj = 0; nj < 2; nj++) {
      int c2 = sel * 64 + half * 32 + nj * 16 + lrow;   // 0..127 in act2
      float s = st[512 + c2], t = st[640 + c2];
#pragma unroll
      for (int r = 0; r < 4; r++) {
        int px = mi * 16 + (l >> 4) * 4 + r;
        float v = fmaxf(acc2[mi][nj][r] * s + t, 0.f);
        act2[((size_t)bb * HWs + p0 + px) * 128 + c2] = (f16)v;
      }
    }
}

// ---------------- attn_final: 8x8 tile attention + fused output projection ----------------
__global__ __launch_bounds__(256) void attn_final(const f16* __restrict__ act1,
                                                  const f16* __restrict__ act2,
                                                  const f16* __restrict__ W3,
                                                  const float* __restrict__ st,
                                                  float* __restrict__ out)
{
  __shared__ float Ps[64 * 52];      // 13,312 B
  __shared__ f16 buf[208 * 136];     // 56,576 B: Qs+Ks -> Vs -> ctxs
  const int tid = threadIdx.x;
  const int l = tid & 63, w = tid >> 6;
  const int bb = blockIdx.z;
  const int x0 = blockIdx.x * 8, y0 = blockIdx.y * 8;
  const f16* a2 = act2 + (size_t)bb * HWs * 128;
  const f16* a1 = act1 + (size_t)bb * HWs * 128;
  f16* Qs = buf;
  f16* Ks = buf + 64 * 72;
  const int lrow = l & 15, lk = (l >> 4) * 8;

  // stage Q (act2 ch 64..127)
#pragma unroll
  for (int it = 0; it < 2; it++) {
    int t = it * 256 + tid;
    int q = t >> 3, seg = t & 7;
    int gp = (y0 + (q >> 3)) * WW + x0 + (q & 7);
    *(f16x8*)&Qs[q * 72 + seg * 8] = *(const f16x8*)&a2[(size_t)gp * 128 + 64 + seg * 8];
  }
  // stage K (act2 ch 0..63), 208 halo rows, zero OOB
  for (int t = tid; t < 1664; t += 256) {
    int kk = t >> 3, seg = t & 7;
    int ky = (kk * 4682) >> 16, kx = kk - 14 * ky;
    int gy = y0 - 3 + ky, gx = x0 - 3 + kx;
    f16x8 v = {(f16)0, (f16)0, (f16)0, (f16)0, (f16)0, (f16)0, (f16)0, (f16)0};
    if (kk < 196 && (unsigned)gy < (unsigned)HH && (unsigned)gx < (unsigned)WW)
      v = *(const f16x8*)&a2[((size_t)(gy * WW + gx)) * 128 + seg * 8];
    *(f16x8*)&Ks[kk * 72 + seg * 8] = v;
  }
  __syncthreads();

  // QK
  f32x4 sc[13];
#pragma unroll
  for (int nj = 0; nj < 13; nj++) sc[nj] = (f32x4){0.f, 0.f, 0.f, 0.f};
#pragma unroll
  for (int ks = 0; ks < 2; ks++) {
    f16x8 aq = *(const f16x8*)&Qs[(w * 16 + lrow) * 72 + ks * 32 + lk];
#pragma unroll
    for (int nj = 0; nj < 13; nj++) {
      f16x8 bk = *(const f16x8*)&Ks[(nj * 16 + lrow) * 72 + ks * 32 + lk];
      sc[nj] = __builtin_amdgcn_mfma_f32_16x16x32_f16(aq, bk, sc[nj], 0, 0, 0);
    }
  }
  // mask non-window cols
  const int r0 = w * 16 + (l >> 4) * 4;
#pragma unroll
  for (int nj = 0; nj < 13; nj++) {
    int c = nj * 16 + lrow;
    int ky = (c * 4682) >> 16, kx = c - 14 * ky;
#pragma unroll
    for (int r = 0; r < 4; r++) {
      int qy = (r0 + r) >> 3, qx = (r0 + r) & 7;
      bool valid = ((unsigned)(ky - qy) < 7u) && ((unsigned)(kx - qx) < 7u);
      if (!valid) sc[nj][r] = -1e30f;
    }
  }
  // softmax per q-row
  float mx[4], sm[4], inv[4];
#pragma unroll
  for (int r = 0; r < 4; r++) {
    mx[r] = -1e30f;
#pragma unroll
    for (int nj = 0; nj < 13; nj++) mx[r] = fmaxf(mx[r], sc[nj][r]);
  }
#pragma unroll
  for (int off = 1; off < 16; off <<= 1)
#pragma unroll
    for (int r = 0; r < 4; r++) mx[r] = fmaxf(mx[r], __shfl_xor(mx[r], off));
#pragma unroll
  for (int r = 0; r < 4; r++) sm[r] = 0.f;
#pragma unroll
  for (int nj = 0; nj < 13; nj++)
#pragma unroll
    for (int r = 0; r < 4; r++) {
      float e = __expf(sc[nj][r] - mx[r]);
      sc[nj][r] = e; sm[r] += e;
    }
#pragma unroll
  for (int off = 1; off < 16; off <<= 1)
#pragma unroll
    for (int r = 0; r < 4; r++) sm[r] += __shfl_xor(sm[r], off);
#pragma unroll
  for (int r = 0; r < 4; r++) inv[r] = 1.0f / sm[r];
#pragma unroll
  for (int nj = 0; nj < 13; nj++) {
    int c = nj * 16 + lrow;
    int ky = (c * 4682) >> 16, kx = c - 14 * ky;
#pragma unroll
    for (int r = 0; r < 4; r++) {
      int qy = (r0 + r) >> 3, qx = (r0 + r) & 7;
      int dy = ky - qy, dx = kx - qx;
      if (((unsigned)dy < 7u) && ((unsigned)dx < 7u))
        Ps[(r0 + r) * 52 + dy * 7 + dx] = sc[nj][r] * inv[r];
    }
  }
  __syncthreads();

  // stage V (act1 ch 0..127)
  f16* Vs = buf;
  for (int t = tid; t < 3328; t += 256) {
    int kk = t >> 4, seg = t & 15;
    int ky = (kk * 4682) >> 16, kx = kk - 14 * ky;
    int gy = y0 - 3 + ky, gx = x0 - 3 + kx;
    f16x8 v = {(f16)0, (f16)0, (f16)0, (f16)0, (f16)0, (f16)0, (f16)0, (f16)0};
    if (kk < 196 && (unsigned)gy < (unsigned)HH && (unsigned)gx < (unsigned)WW)
      v = *(const f16x8*)&a1[((size_t)(gy * WW + gx)) * 128 + seg * 8];
    *(f16x8*)&Vs[kk * 136 + seg * 8] = v;
  }
  __syncthreads();

  // PV (VALU, f32 acc): thread = (pixel q, 32-ch chunk)
  const int q = tid >> 2;
  const int qy = q >> 3, qx = q & 7;
  const int ch0 = (tid & 3) * 32;
  float acc[32];
#pragma unroll
  for (int i = 0; i < 32; i++) acc[i] = 0.f;
#pragma unroll
  for (int dy = 0; dy < 7; dy++)
#pragma unroll
    for (int dx = 0; dx < 7; dx++) {
      float p = Ps[q * 52 + dy * 7 + dx];
      int kk = (qy + dy) * 14 + qx + dx;
      const f16* vp = &Vs[kk * 136 + ch0];
#pragma unroll
      for (int s = 0; s < 4; s++) {
        f16x8 v = *(const f16x8*)&vp[s * 8];
#pragma unroll
        for (int j = 0; j < 8; j++) acc[s * 8 + j] += (float)v[j] * p;
      }
    }
  __syncthreads();   // all PV reads of Vs complete before ctx overwrite

  // ctx -> LDS (reuse buf)
  f16* ctxs = buf;
#pragma unroll
  for (int s = 0; s < 4; s++) {
    f16x8 o;
#pragma unroll
    for (int j = 0; j < 8; j++) o[j] = (f16)acc[s * 8 + j];
    *(f16x8*)&ctxs[q * 136 + ch0 + s * 8] = o;
  }
  __syncthreads();

  // final projection: wave w -> couts [64w, 64w+64); A = W3 (global/L2), B = ctx^T (LDS)
  f32x4 fac[4][4];
#pragma unroll
  for (int i = 0; i < 4; i++)
#pragma unroll
    for (int j = 0; j < 4; j++) fac[i][j] = (f32x4){0.f, 0.f, 0.f, 0.f};
#pragma unroll
  for (int ks = 0; ks < 4; ks++) {
    f16x8 a3[4], b3[4];
#pragma unroll
    for (int mi = 0; mi < 4; mi++)
      a3[mi] = *(const f16x8*)&W3[(size_t)(w * 64 + mi * 16 + lrow) * 128 + ks * 32 + lk];
#pragma unroll
    for (int nj = 0; nj < 4; nj++)
      b3[nj] = *(const f16x8*)&ctxs[(nj * 16 + lrow) * 136 + ks * 32 + lk];
#pragma unroll
    for (int mi = 0; mi < 4; mi++)
#pragma unroll
      for (int nj = 0; nj < 4; nj++)
        fac[mi][nj] = __builtin_amdgcn_mfma_f32_16x16x32_f16(a3[mi], b3[nj], fac[mi][nj], 0, 0, 0);
  }
#pragma unroll
  for (int mi = 0; mi < 4; mi++)
#pragma unroll
    for (int nj = 0; nj < 4; nj++) {
#pragma unroll
      for (int r = 0; r < 4; r++) {
        int cout = w * 64 + mi * 16 + (l >> 4) * 4 + r;
        int px = nj * 16 + lrow;
        int gp = (y0 + (px >> 3)) * WW + x0 + (px & 7);
        out[((size_t)bb * 256 + cout) * HWs + gp] = fac[mi][nj][r] + st[768 + cout];
      }
    }
}

extern "C" void kernel_launch(void* const* d_in, const int* in_sizes, int n_in,
                              void* d_out, int out_size, void* d_ws, size_t ws_size,
                              hipStream_t stream) {
  (void)in_sizes; (void)n_in; (void)out_size; (void)ws_size;
  const float* x      = (const float*)d_in[0];
  const float* fk_w1  = (const float*)d_in[1];
  const float* fk_b1  = (const float*)d_in[2];
  const float* fk_bn1 = (const float*)d_in[3];
  const float* fk_w2  = (const float*)d_in[4];
  const float* fk_b2  = (const float*)d_in[5];
  const float* fk_bn2 = (const float*)d_in[6];
  const float* fq_w1  = (const float*)d_in[7];
  const float* fq_b1  = (const float*)d_in[8];
  const float* fq_bn1 = (const float*)d_in[9];
  const float* fq_w2  = (const float*)d_in[10];
  const float* fq_b2  = (const float*)d_in[11];
  const float* fq_bn2 = (const float*)d_in[12];
  const float* fv_w   = (const float*)d_in[13];
  const float* fv_b   = (const float*)d_in[14];
  const float* W_w    = (const float*)d_in[15];
  const float* W_b    = (const float*)d_in[16];
  char* wsb = (char*)d_ws;
  float* out = (float*)d_out;

  f16* act1 = (f16*)(wsb + OFF_ACT1);
  f16* act2 = (f16*)(wsb + OFF_ACT2);
  f16* w1   = (f16*)(wsb + OFF_W1);
  f16* w2   = (f16*)(wsb + OFF_W2);
  f16* w3   = (f16*)(wsb + OFF_W3);
  float* st = (float*)(wsb + OFF_ST);

  prep_kernel<<<dim3(419), dim3(256), 0, stream>>>(
      fk_w1, fk_b1, fk_bn1, fk_w2, fk_b2, fk_bn2,
      fq_w1, fq_b1, fq_bn1, fq_w2, fq_b2, fq_bn2, fv_w, fv_b, W_w, W_b, wsb);

  conv12<<<dim3(288, 2), dim3(256), 0, stream>>>(x, w1, w2, act1, act2, st);

  attn_final<<<dim3(12, 12, 2), dim3(256), 0, stream>>>(act1, act2, w3, st, out);
}